// Round 1
// baseline (59548.737 us; speedup 1.0000x reference)
//
#include <hip/hip_runtime.h>
#include <math.h>

#define B_ 2
#define N_ 25000
#define E_ 400000
#define D_ 128
#define NRBF 64
#define TE 8          // edges per tile
#define EPB 320       // edges per block (E_ % EPB == 0, EPB % TE == 0)
#define NCHUNK (E_ / EPB)

// shifted softplus: softplus(x) - ln(2), numerically stable
__device__ __forceinline__ float ssp(float x) {
    return fmaxf(x, 0.0f) + __logf(1.0f + __expf(-fabsf(x))) - 0.69314718056f;
}

__global__ __launch_bounds__(128, 2)
void cfconv_kernel(const float* __restrict__ af,      // [B,N,D]
                   const float* __restrict__ dist,    // [B,E]
                   const int*   __restrict__ idx_j,   // [E]
                   const int*   __restrict__ seg_i,   // [E] (sorted)
                   const float* __restrict__ centers, // [NRBF]
                   const float* __restrict__ gam,     // [NRBF]
                   const float* __restrict__ W1,      // [NRBF,D]
                   const float* __restrict__ b1,      // [D]
                   const float* __restrict__ W2,      // [D,D]
                   const float* __restrict__ b2,      // [D]
                   float* __restrict__ out)           // [B,N,D]
{
    const int t = threadIdx.x;     // 0..127
    const int d = t;               // feature dim owned by this thread
    const int b = blockIdx.y;
    const int e0   = blockIdx.x * EPB;
    const int eEnd = e0 + EPB;     // E_ % EPB == 0, always full

    __shared__ __align__(16) float rbf_t[NRBF][TE];  // [k][e]
    __shared__ __align__(16) float h1_t[D_][TE];     // [k][e]

    // ---- preload weights into registers (shared across all edges of block)
    float wa[NRBF];
    #pragma unroll
    for (int k = 0; k < NRBF; ++k) wa[k] = W1[k * D_ + d];
    float wb[D_];
    #pragma unroll
    for (int k = 0; k < D_; ++k) wb[k] = W2[k * D_ + d];
    const float bias1 = b1[d];
    const float bias2 = b2[d];

    // rbf params for this thread's k-row (k = t & 63); wave-uniform edge half
    const int   krb = t & 63;
    const float gk  = gam[krb];
    const float ck  = centers[krb];
    const int   eh  = t >> 6;      // 0 for wave0, 1 for wave1

    const float* dist_b = dist + (size_t)b * E_;
    const float* af_b   = af   + (size_t)b * N_ * D_;
    float*       out_b  = out  + (size_t)b * N_ * D_;

    int   cur_seg = -1;
    float pending = 0.0f;

    for (int te = e0; te < eEnd; te += TE) {
        // ---- RBF expansion for 8 edges into LDS (each thread: its k, 4 edges)
        float r0, r1, r2, r3;
        {
            const int eb = te + eh * 4;
            float x0 = dist_b[eb + 0] - ck;
            float x1 = dist_b[eb + 1] - ck;
            float x2 = dist_b[eb + 2] - ck;
            float x3 = dist_b[eb + 3] - ck;
            r0 = __expf(-gk * x0 * x0);
            r1 = __expf(-gk * x1 * x1);
            r2 = __expf(-gk * x2 * x2);
            r3 = __expf(-gk * x3 * x3);
        }
        *(float4*)&rbf_t[krb][eh * 4] = make_float4(r0, r1, r2, r3);
        __syncthreads();   // (A) rbf visible

        // ---- GEMM1: h1[d][e] = sum_k rbf[k][e] * W1[k][d]
        float acc0 = 0.f, acc1 = 0.f, acc2 = 0.f, acc3 = 0.f;
        float acc4 = 0.f, acc5 = 0.f, acc6 = 0.f, acc7 = 0.f;
        #pragma unroll
        for (int k = 0; k < NRBF; ++k) {
            const float4 ra = *(const float4*)&rbf_t[k][0];
            const float4 rb = *(const float4*)&rbf_t[k][4];
            const float  w  = wa[k];
            acc0 = fmaf(w, ra.x, acc0);
            acc1 = fmaf(w, ra.y, acc1);
            acc2 = fmaf(w, ra.z, acc2);
            acc3 = fmaf(w, ra.w, acc3);
            acc4 = fmaf(w, rb.x, acc4);
            acc5 = fmaf(w, rb.y, acc5);
            acc6 = fmaf(w, rb.z, acc6);
            acc7 = fmaf(w, rb.w, acc7);
        }
        // ssp + stage h1 (this thread's row d)
        float4 h0, h1v;
        h0.x  = ssp(acc0 + bias1);
        h0.y  = ssp(acc1 + bias1);
        h0.z  = ssp(acc2 + bias1);
        h0.w  = ssp(acc3 + bias1);
        h1v.x = ssp(acc4 + bias1);
        h1v.y = ssp(acc5 + bias1);
        h1v.z = ssp(acc6 + bias1);
        h1v.w = ssp(acc7 + bias1);
        *(float4*)&h1_t[d][0] = h0;
        *(float4*)&h1_t[d][4] = h1v;
        __syncthreads();   // (B) h1 visible

        // ---- GEMM2: f[d][e] = sum_k h1[k][e] * W2[k][d]
        float f0 = 0.f, f1 = 0.f, f2 = 0.f, f3 = 0.f;
        float f4 = 0.f, f5 = 0.f, f6 = 0.f, f7 = 0.f;
        #pragma unroll
        for (int k = 0; k < D_; ++k) {
            const float4 ha = *(const float4*)&h1_t[k][0];
            const float4 hb = *(const float4*)&h1_t[k][4];
            const float  w  = wb[k];
            f0 = fmaf(w, ha.x, f0);
            f1 = fmaf(w, ha.y, f1);
            f2 = fmaf(w, ha.z, f2);
            f3 = fmaf(w, ha.w, f3);
            f4 = fmaf(w, hb.x, f4);
            f5 = fmaf(w, hb.y, f5);
            f6 = fmaf(w, hb.z, f6);
            f7 = fmaf(w, hb.w, f7);
        }
        float fv[TE] = { ssp(f0 + bias2), ssp(f1 + bias2), ssp(f2 + bias2), ssp(f3 + bias2),
                         ssp(f4 + bias2), ssp(f5 + bias2), ssp(f6 + bias2), ssp(f7 + bias2) };

        // ---- gather neighbor feature, multiply, segment-combine, scatter
        #pragma unroll
        for (int i = 0; i < TE; ++i) {
            const int e  = te + i;
            const int j  = idx_j[e];   // wave-uniform -> scalar load
            const int sg = seg_i[e];   // wave-uniform, sorted
            const float nb  = af_b[(size_t)j * D_ + d];
            const float msg = nb * fv[i];
            if (sg != cur_seg) {
                if (cur_seg >= 0)
                    atomicAdd(&out_b[(size_t)cur_seg * D_ + d], pending);
                cur_seg = sg;
                pending = msg;
            } else {
                pending += msg;
            }
        }
        // no extra barrier needed: next tile's rbf write is ordered after (B)
    }
    if (cur_seg >= 0)
        atomicAdd(&out_b[(size_t)cur_seg * D_ + d], pending);
}

extern "C" void kernel_launch(void* const* d_in, const int* in_sizes, int n_in,
                              void* d_out, int out_size, void* d_ws, size_t ws_size,
                              hipStream_t stream) {
    const float* af      = (const float*)d_in[0];
    const float* dist    = (const float*)d_in[1];
    const int*   idx_j   = (const int*)d_in[2];
    const int*   seg_i   = (const int*)d_in[3];
    const float* centers = (const float*)d_in[4];
    const float* gam     = (const float*)d_in[5];
    const float* W1      = (const float*)d_in[6];
    const float* b1      = (const float*)d_in[7];
    const float* W2      = (const float*)d_in[8];
    const float* b2      = (const float*)d_in[9];
    float* out = (float*)d_out;

    hipMemsetAsync(out, 0, (size_t)out_size * sizeof(float), stream);

    dim3 grid(NCHUNK, B_);
    cfconv_kernel<<<grid, 128, 0, stream>>>(af, dist, idx_j, seg_i,
                                            centers, gam, W1, b1, W2, b2, out);
}

// Round 2
// 56979.608 us; speedup vs baseline: 1.0451x; 1.0451x over previous
//
#include <hip/hip_runtime.h>
#include <math.h>

#define B_ 2
#define N_ 25000
#define E_ 400000
#define D_ 128
#define NRBF 64
#define TE 8          // edges per tile
#define EPB 160       // edges per block (E_ % EPB == 0, EPB % TE == 0)
#define NCHUNK (E_ / EPB)   // 2500 blocks per batch

// 32-wide float vectors: first-class SSA values -> guaranteed VGPRs, no alloca.
typedef float vf32 __attribute__((ext_vector_type(32)));

// shifted softplus: softplus(x) - ln(2), numerically stable
__device__ __forceinline__ float ssp(float x) {
    return fmaxf(x, 0.0f) + __logf(1.0f + __expf(-fabsf(x))) - 0.69314718056f;
}

__global__ __launch_bounds__(128, 2)
void cfconv_kernel(const float* __restrict__ af,      // [B,N,D]
                   const float* __restrict__ dist,    // [B,E]
                   const int*   __restrict__ idx_j,   // [E]
                   const int*   __restrict__ seg_i,   // [E] (sorted)
                   const float* __restrict__ centers, // [NRBF]
                   const float* __restrict__ gam,     // [NRBF]
                   const float* __restrict__ W1,      // [NRBF,D]
                   const float* __restrict__ b1,      // [D]
                   const float* __restrict__ W2,      // [D,D]
                   const float* __restrict__ b2,      // [D]
                   float* __restrict__ out)           // [B,N,D]
{
    const int t = threadIdx.x;     // 0..127
    const int d = t;               // feature dim owned by this thread
    const int b = blockIdx.y;
    const int e0   = blockIdx.x * EPB;
    const int eEnd = e0 + EPB;

    __shared__ __align__(16) float rbf_t[NRBF][TE];  // [k][e]
    __shared__ __align__(16) float h1_t[D_][TE];     // [k][e]

    // ---- weight columns in register vectors (no alloca -> no scratch)
    vf32 wa0, wa1;            // W1[:,d], k = 0..31 / 32..63
    vf32 wb0, wb1, wb2, wb3;  // W2[:,d], k = 0..31 / .. / 96..127
    #pragma unroll
    for (int k = 0; k < 32; ++k) {
        wa0[k] = W1[(k      ) * D_ + d];
        wa1[k] = W1[(k + 32 ) * D_ + d];
    }
    #pragma unroll
    for (int k = 0; k < 32; ++k) {
        wb0[k] = W2[(k      ) * D_ + d];
        wb1[k] = W2[(k + 32 ) * D_ + d];
        wb2[k] = W2[(k + 64 ) * D_ + d];
        wb3[k] = W2[(k + 96 ) * D_ + d];
    }
    const float bias1 = b1[d];
    const float bias2 = b2[d];

    // rbf params for this thread's k-row (k = t & 63)
    const int   krb = t & 63;
    const float gk  = gam[krb];
    const float ck  = centers[krb];
    const int   eh  = t >> 6;      // 0 for wave0, 1 for wave1

    const float* dist_b = dist + (size_t)b * E_;
    const float* af_b   = af   + (size_t)b * N_ * D_;
    float*       out_b  = out  + (size_t)b * N_ * D_;

    int   cur_seg = -1;
    float pending = 0.0f;

    for (int te = e0; te < eEnd; te += TE) {
        // ---- RBF expansion: each thread computes its k for 4 edges
        {
            const int eb = te + eh * 4;
            float x0 = dist_b[eb + 0] - ck;
            float x1 = dist_b[eb + 1] - ck;
            float x2 = dist_b[eb + 2] - ck;
            float x3 = dist_b[eb + 3] - ck;
            float r0 = __expf(-gk * x0 * x0);
            float r1 = __expf(-gk * x1 * x1);
            float r2 = __expf(-gk * x2 * x2);
            float r3 = __expf(-gk * x3 * x3);
            *(float4*)&rbf_t[krb][eh * 4] = make_float4(r0, r1, r2, r3);
        }
        __syncthreads();   // (A) rbf visible

        // ---- GEMM1: h1[d][e] = sum_k rbf[k][e] * W1[k][d]
        float acc0 = 0.f, acc1 = 0.f, acc2 = 0.f, acc3 = 0.f;
        float acc4 = 0.f, acc5 = 0.f, acc6 = 0.f, acc7 = 0.f;
        #define G1_BODY(W, KOFF)                                   \
        {                                                          \
            const float4 ra = *(const float4*)&rbf_t[(KOFF)][0];   \
            const float4 rb = *(const float4*)&rbf_t[(KOFF)][4];   \
            acc0 = fmaf((W), ra.x, acc0);                          \
            acc1 = fmaf((W), ra.y, acc1);                          \
            acc2 = fmaf((W), ra.z, acc2);                          \
            acc3 = fmaf((W), ra.w, acc3);                          \
            acc4 = fmaf((W), rb.x, acc4);                          \
            acc5 = fmaf((W), rb.y, acc5);                          \
            acc6 = fmaf((W), rb.z, acc6);                          \
            acc7 = fmaf((W), rb.w, acc7);                          \
        }
        #pragma unroll
        for (int k = 0; k < 32; ++k) G1_BODY(wa0[k], k);
        #pragma unroll
        for (int k = 0; k < 32; ++k) G1_BODY(wa1[k], k + 32);

        // ssp + stage h1 (this thread's row d)
        float4 h0, h1v;
        h0.x  = ssp(acc0 + bias1);
        h0.y  = ssp(acc1 + bias1);
        h0.z  = ssp(acc2 + bias1);
        h0.w  = ssp(acc3 + bias1);
        h1v.x = ssp(acc4 + bias1);
        h1v.y = ssp(acc5 + bias1);
        h1v.z = ssp(acc6 + bias1);
        h1v.w = ssp(acc7 + bias1);
        *(float4*)&h1_t[d][0] = h0;
        *(float4*)&h1_t[d][4] = h1v;
        __syncthreads();   // (B) h1 visible

        // ---- GEMM2: f[d][e] = sum_k h1[k][e] * W2[k][d]
        float f0 = 0.f, f1 = 0.f, f2 = 0.f, f3 = 0.f;
        float f4 = 0.f, f5 = 0.f, f6 = 0.f, f7 = 0.f;
        #define G2_BODY(W, KOFF)                                   \
        {                                                          \
            const float4 ha = *(const float4*)&h1_t[(KOFF)][0];    \
            const float4 hb = *(const float4*)&h1_t[(KOFF)][4];    \
            f0 = fmaf((W), ha.x, f0);                              \
            f1 = fmaf((W), ha.y, f1);                              \
            f2 = fmaf((W), ha.z, f2);                              \
            f3 = fmaf((W), ha.w, f3);                              \
            f4 = fmaf((W), hb.x, f4);                              \
            f5 = fmaf((W), hb.y, f5);                              \
            f6 = fmaf((W), hb.z, f6);                              \
            f7 = fmaf((W), hb.w, f7);                              \
        }
        #pragma unroll
        for (int k = 0; k < 32; ++k) G2_BODY(wb0[k], k);
        #pragma unroll
        for (int k = 0; k < 32; ++k) G2_BODY(wb1[k], k + 32);
        #pragma unroll
        for (int k = 0; k < 32; ++k) G2_BODY(wb2[k], k + 64);
        #pragma unroll
        for (int k = 0; k < 32; ++k) G2_BODY(wb3[k], k + 96);

        const float fv0 = ssp(f0 + bias2), fv1 = ssp(f1 + bias2);
        const float fv2 = ssp(f2 + bias2), fv3 = ssp(f3 + bias2);
        const float fv4 = ssp(f4 + bias2), fv5 = ssp(f5 + bias2);
        const float fv6 = ssp(f6 + bias2), fv7 = ssp(f7 + bias2);

        // ---- gather neighbor feature, multiply, segment-combine, scatter
        #define GATHER_STEP(I, F)                                              \
        {                                                                      \
            const int e  = te + (I);                                           \
            const int j  = idx_j[e];                                           \
            const int sg = seg_i[e];                                           \
            const float nb  = af_b[(size_t)j * D_ + d];                        \
            const float msg = nb * (F);                                        \
            if (sg != cur_seg) {                                               \
                if (cur_seg >= 0)                                              \
                    atomicAdd(&out_b[(size_t)cur_seg * D_ + d], pending);      \
                cur_seg = sg;                                                  \
                pending = msg;                                                 \
            } else {                                                           \
                pending += msg;                                                \
            }                                                                  \
        }
        GATHER_STEP(0, fv0)
        GATHER_STEP(1, fv1)
        GATHER_STEP(2, fv2)
        GATHER_STEP(3, fv3)
        GATHER_STEP(4, fv4)
        GATHER_STEP(5, fv5)
        GATHER_STEP(6, fv6)
        GATHER_STEP(7, fv7)
    }
    if (cur_seg >= 0)
        atomicAdd(&out_b[(size_t)cur_seg * D_ + d], pending);
}

extern "C" void kernel_launch(void* const* d_in, const int* in_sizes, int n_in,
                              void* d_out, int out_size, void* d_ws, size_t ws_size,
                              hipStream_t stream) {
    const float* af      = (const float*)d_in[0];
    const float* dist    = (const float*)d_in[1];
    const int*   idx_j   = (const int*)d_in[2];
    const int*   seg_i   = (const int*)d_in[3];
    const float* centers = (const float*)d_in[4];
    const float* gam     = (const float*)d_in[5];
    const float* W1      = (const float*)d_in[6];
    const float* b1      = (const float*)d_in[7];
    const float* W2      = (const float*)d_in[8];
    const float* b2      = (const float*)d_in[9];
    float* out = (float*)d_out;

    hipMemsetAsync(out, 0, (size_t)out_size * sizeof(float), stream);

    dim3 grid(NCHUNK, B_);
    cfconv_kernel<<<grid, 128, 0, stream>>>(af, dist, idx_j, seg_i,
                                            centers, gam, W1, b1, W2, b2, out);
}

// Round 3
// 1019.565 us; speedup vs baseline: 58.4060x; 55.8862x over previous
//
#include <hip/hip_runtime.h>
#include <math.h>

#define B_ 2
#define N_ 25000
#define E_ 400000
#define D_ 128
#define NRBF 64

#define TPB 256                // threads per block (4 waves)
#define TILE 64                // edges per tile-step
#define NTILES 50              // tile-steps per block
#define EPB (TILE * NTILES)    // 3200 edges per block
#define CHUNK (EPB / 16)       // 200 contiguous edges owned by each equad lane-group
#define NBLK (E_ / EPB)        // 125 blocks per batch
#define SR 68                  // rbf_t row stride (words) -> 272B, b128-aligned
#define SH 68                  // h1_t  row stride

typedef float vf8 __attribute__((ext_vector_type(8)));

// shifted softplus: softplus(x) - ln(2)
__device__ __forceinline__ float ssp(float x) {
    return fmaxf(x, 0.0f) + __logf(1.0f + __expf(-fabsf(x))) - 0.69314718056f;
}
__device__ __forceinline__ vf8 ssp8(vf8 x) {
    vf8 r;
    #pragma unroll
    for (int i = 0; i < 8; ++i) r[i] = ssp(x[i]);
    return r;
}

__global__ __launch_bounds__(TPB, 1)
void cfconv_kernel(const float* __restrict__ af,      // [B,N,D]
                   const float* __restrict__ dist,    // [B,E]
                   const int*   __restrict__ idx_j,   // [E]
                   const int*   __restrict__ seg_i,   // [E] (sorted)
                   const float* __restrict__ centers, // [NRBF]
                   const float* __restrict__ gam,     // [NRBF]
                   const float* __restrict__ W1,      // [NRBF,D]
                   const float* __restrict__ b1,      // [D]
                   const float* __restrict__ W2,      // [D,D]
                   const float* __restrict__ b2,      // [D]
                   float* __restrict__ out)           // [B,N,D]
{
    const int t = threadIdx.x;            // 0..255
    const int b = blockIdx.y;
    const int e0 = blockIdx.x * EPB;

    const int equad  = t & 15;            // which 4-edge group (16 groups)
    const int dchunk = t >> 4;            // which 8-dim group  (16 groups)
    const int d0     = dchunk * 8;

    __shared__ float W1s[NRBF][D_];       // 32 KB
    __shared__ float W2s[D_][D_];         // 64 KB
    __shared__ float rbf_t[NRBF][SR];     // 17.4 KB  [k][edge-slot]
    __shared__ float h1_t [D_  ][SH];     // 34.8 KB  [k2][edge-slot]

    // ---- stage weights into LDS (coalesced float4), once per block
    {
        const float4* W1v = (const float4*)W1;
        float4* W1sv = (float4*)&W1s[0][0];
        #pragma unroll
        for (int i = 0; i < (NRBF * D_ / 4) / TPB; ++i)   // 8 iters
            W1sv[t + i * TPB] = W1v[t + i * TPB];
        const float4* W2v = (const float4*)W2;
        float4* W2sv = (float4*)&W2s[0][0];
        #pragma unroll
        for (int i = 0; i < (D_ * D_ / 4) / TPB; ++i)     // 16 iters
            W2sv[t + i * TPB] = W2v[t + i * TPB];
    }

    const vf8 b1v = *(const vf8*)&b1[d0];
    const vf8 b2v = *(const vf8*)&b2[d0];

    // rbf params for this thread's k-row
    const int   krb = t & 63;
    const float gk  = gam[krb];
    const float ck  = centers[krb];
    const int   sb  = (t >> 6) * 16;      // this wave's 16 edge-slots

    const float* dist_b = dist + (size_t)b * E_;
    const float* af_b   = af   + (size_t)b * N_ * D_;
    float*       out_b  = out  + (size_t)b * N_ * D_;

    __syncthreads();                      // weights visible

    int cur_seg = -1;
    vf8 pend = (vf8)0.0f;

    const int myebase = e0 + equad * CHUNK;   // this thread's contiguous chunk

    for (int tl = 0; tl < NTILES; ++tl) {
        const int te = tl * 4;            // offset within each 200-edge chunk

        // ---- RBF: thread computes its k for 16 edge-slots (4 quads x 4)
        #pragma unroll
        for (int q = 0; q < 4; ++q) {
            const int eq = (sb >> 2) + q;
            const int eb = e0 + eq * CHUNK + te;
            float x0 = dist_b[eb + 0] - ck;
            float x1 = dist_b[eb + 1] - ck;
            float x2 = dist_b[eb + 2] - ck;
            float x3 = dist_b[eb + 3] - ck;
            float4 r;
            r.x = __expf(-gk * x0 * x0);
            r.y = __expf(-gk * x1 * x1);
            r.z = __expf(-gk * x2 * x2);
            r.w = __expf(-gk * x3 * x3);
            *(float4*)&rbf_t[krb][sb + q * 4] = r;
        }
        __syncthreads();                  // (A) rbf ready

        // ---- GEMM1: h1[e][d] = sum_k rbf[k][e] * W1[k][d]
        vf8 a0 = (vf8)0.0f, a1 = (vf8)0.0f, a2 = (vf8)0.0f, a3 = (vf8)0.0f;
        #pragma unroll 16
        for (int k = 0; k < NRBF; ++k) {
            const float4 r = *(const float4*)&rbf_t[k][equad * 4];
            const vf8    w = *(const vf8*)&W1s[k][d0];
            a0 += r.x * w;
            a1 += r.y * w;
            a2 += r.z * w;
            a3 += r.w * w;
        }
        const vf8 h0 = ssp8(a0 + b1v);
        const vf8 h1 = ssp8(a1 + b1v);
        const vf8 h2 = ssp8(a2 + b1v);
        const vf8 h3 = ssp8(a3 + b1v);

        // transpose-store h1 into [k2][edge] layout
        #pragma unroll
        for (int jj = 0; jj < 8; ++jj) {
            float* row = &h1_t[d0 + jj][equad * 4];
            row[0] = h0[jj]; row[1] = h1[jj]; row[2] = h2[jj]; row[3] = h3[jj];
        }
        __syncthreads();                  // (B) h1 ready

        // ---- GEMM2: f[e][d] = sum_k2 h1[k2][e] * W2[k2][d]
        vf8 f0 = (vf8)0.0f, f1 = (vf8)0.0f, f2 = (vf8)0.0f, f3 = (vf8)0.0f;
        #pragma unroll 16
        for (int k = 0; k < D_; ++k) {
            const float4 h = *(const float4*)&h1_t[k][equad * 4];
            const vf8    w = *(const vf8*)&W2s[k][d0];
            f0 += h.x * w;
            f1 += h.y * w;
            f2 += h.z * w;
            f3 += h.w * w;
        }
        const vf8 g0 = ssp8(f0 + b2v);
        const vf8 g1 = ssp8(f1 + b2v);
        const vf8 g2 = ssp8(f2 + b2v);
        const vf8 g3 = ssp8(f3 + b2v);

        // ---- gather * filter, segment run-combine, atomic flush
        const int eb = myebase + te;
        #define EDGE_STEP(I, G)                                                 \
        {                                                                       \
            const int e  = eb + (I);                                            \
            const int j  = idx_j[e];                                            \
            const int sg = seg_i[e];                                            \
            const vf8 nb = *(const vf8*)&af_b[(size_t)j * D_ + d0];             \
            const vf8 msg = nb * (G);                                           \
            if (sg != cur_seg) {                                                \
                if (cur_seg >= 0) {                                             \
                    float* o = &out_b[(size_t)cur_seg * D_ + d0];               \
                    _Pragma("unroll")                                           \
                    for (int jj = 0; jj < 8; ++jj) atomicAdd(o + jj, pend[jj]); \
                }                                                               \
                cur_seg = sg;                                                   \
                pend = msg;                                                     \
            } else {                                                            \
                pend += msg;                                                    \
            }                                                                   \
        }
        EDGE_STEP(0, g0)
        EDGE_STEP(1, g1)
        EDGE_STEP(2, g2)
        EDGE_STEP(3, g3)
        #undef EDGE_STEP
        // no barrier here: next rbf write is ordered after (B) for all threads
    }
    if (cur_seg >= 0) {
        float* o = &out_b[(size_t)cur_seg * D_ + d0];
        #pragma unroll
        for (int jj = 0; jj < 8; ++jj) atomicAdd(o + jj, pend[jj]);
    }
}

extern "C" void kernel_launch(void* const* d_in, const int* in_sizes, int n_in,
                              void* d_out, int out_size, void* d_ws, size_t ws_size,
                              hipStream_t stream) {
    const float* af      = (const float*)d_in[0];
    const float* dist    = (const float*)d_in[1];
    const int*   idx_j   = (const int*)d_in[2];
    const int*   seg_i   = (const int*)d_in[3];
    const float* centers = (const float*)d_in[4];
    const float* gam     = (const float*)d_in[5];
    const float* W1      = (const float*)d_in[6];
    const float* b1      = (const float*)d_in[7];
    const float* W2      = (const float*)d_in[8];
    const float* b2      = (const float*)d_in[9];
    float* out = (float*)d_out;

    hipMemsetAsync(out, 0, (size_t)out_size * sizeof(float), stream);

    dim3 grid(NBLK, B_);
    cfconv_kernel<<<grid, TPB, 0, stream>>>(af, dist, idx_j, seg_i,
                                            centers, gam, W1, b1, W2, b2, out);
}

// Round 4
// 281.931 us; speedup vs baseline: 211.2174x; 3.6164x over previous
//
#include <hip/hip_runtime.h>
#include <math.h>

#define B_ 2
#define N_ 25000
#define E_ 400000
#define D_ 128
#define NRBF 64

#define TPB 256               // 4 waves
#define TILE 64               // edges per tile-step (16/wave)
#define NTILES 25
#define EPB (TILE * NTILES)   // 1600 edges per block
#define WCH (EPB / 4)         // 400 edges per wave
#define GCH (EPB / 16)        // 100 edges per (wave, lane-quad) chunk
#define NBLK (E_ / EPB)       // 250 blocks per batch

typedef short bf8   __attribute__((ext_vector_type(8)));   // MFMA A/B frag (8 bf16)
typedef float f32x4 __attribute__((ext_vector_type(4)));   // MFMA C/D frag
typedef float vf8   __attribute__((ext_vector_type(8)));
typedef float vf16  __attribute__((ext_vector_type(16)));

// f32 -> bf16 bits, round-nearest-even
__device__ __forceinline__ short f2bf(float f) {
    union { float f; unsigned u; } v; v.f = f;
    unsigned r = (v.u + 0x7FFFu + ((v.u >> 16) & 1u)) >> 16;
    return (short)r;
}
// shifted softplus: softplus(x) - ln(2)
__device__ __forceinline__ float ssp(float x) {
    return fmaxf(x, 0.0f) + __logf(1.0f + __expf(-fabsf(x))) - 0.69314718056f;
}

__global__ __launch_bounds__(TPB, 2)
void cfconv_kernel(const float* __restrict__ af,      // [B,N,D]
                   const float* __restrict__ dist,    // [B,E]
                   const int*   __restrict__ idx_j,   // [E]
                   const int*   __restrict__ seg_i,   // [E] (sorted)
                   const float* __restrict__ centers, // [NRBF]
                   const float* __restrict__ gam,     // [NRBF]
                   const float* __restrict__ W1,      // [NRBF,D]
                   const float* __restrict__ b1,      // [D]
                   const float* __restrict__ W2,      // [D,D]
                   const float* __restrict__ b2,      // [D]
                   float* __restrict__ out)           // [B,N,D]
{
    const int t    = threadIdx.x;        // 0..255
    const int lane = t & 63;
    const int w    = t >> 6;             // wave id 0..3
    const int g    = lane >> 4;          // lane quad 0..3
    const int c0   = lane & 15;
    const int b    = blockIdx.y;
    const int e0   = blockIdx.x * EPB;

    // fragment-ready bf16 weights: [c][g][n][j] ; B[k][n], k = c*32+g*8+j
    __shared__ __align__(16) short W1f[2 * 4 * D_ * 8];     // 16 KB
    __shared__ __align__(16) short W2f[4 * 4 * D_ * 8];     // 32 KB
    __shared__ __align__(16) short A1 [4 * 2 * 4 * 16 * 8]; //  8 KB [w][c][g][m][j]
    __shared__ __align__(16) short A2 [4 * 4 * 4 * 16 * 8]; // 16 KB [w][c][g][m][j]
    __shared__ float gs[NRBF], cs[NRBF];

    // ---- prep: weights -> bf16 fragment layout (once per block)
    for (int i = t; i < NRBF * D_; i += TPB) {
        const int k = i >> 7, n = i & 127;
        W1f[(((k >> 5) * 4 + ((k >> 3) & 3)) * D_ + n) * 8 + (k & 7)] = f2bf(W1[i]);
    }
    for (int i = t; i < D_ * D_; i += TPB) {
        const int k = i >> 7, n = i & 127;
        W2f[(((k >> 5) * 4 + ((k >> 3) & 3)) * D_ + n) * 8 + (k & 7)] = f2bf(W2[i]);
    }
    if (t < NRBF) { gs[t] = gam[t]; cs[t] = centers[t]; }
    __syncthreads();

    // ---- per-lane constants
    vf8 b1r, b2r;
    #pragma unroll
    for (int nt = 0; nt < 8; ++nt) {
        b1r[nt] = b1[nt * 16 + c0];
        b2r[nt] = b2[nt * 16 + c0];
    }
    // rbf params for this thread's 16-k slice (phase A role: el = t>>2, kq = t&3)
    const int el = t >> 2, kq = t & 3;
    const int we = el >> 4, me = el & 15;
    vf16 gkr, ckr;
    #pragma unroll
    for (int kk = 0; kk < 16; ++kk) { gkr[kk] = gs[kq * 16 + kk]; ckr[kk] = cs[kq * 16 + kk]; }

    const float* dist_b = dist + (size_t)b * E_;
    const float* af_b   = af   + (size_t)b * N_ * D_;
    float*       out_b  = out  + (size_t)b * N_ * D_;

    const int ebase = e0 + w * WCH + g * GCH;   // this lane-quad's contiguous chunk

    int cur_seg = -1;
    vf8 pend = (vf8)0.0f;

    for (int s = 0; s < NTILES; ++s) {
        // ===== Phase A: RBF for 64 edges x 64 k, bf16, A-frag layout =====
        {
            const int e = e0 + we * WCH + (me >> 2) * GCH + s * 4 + (me & 3);
            const float dd = dist_b[e];
            short rb[16];
            #pragma unroll
            for (int kk = 0; kk < 16; ++kk) {
                const float x = dd - ckr[kk];
                rb[kk] = f2bf(__expf(-gkr[kk] * x * x));
            }
            // k = kq*16+kk -> c = kq>>1, g2 = (kq&1)*2 + (kk>>3), j = kk&7
            bf8 lo, hi;
            #pragma unroll
            for (int j = 0; j < 8; ++j) { lo[j] = rb[j]; hi[j] = rb[8 + j]; }
            const int base = (((we * 2 + (kq >> 1)) * 4 + (kq & 1) * 2) * 16 + me) * 8;
            *(bf8*)&A1[base]            = lo;   // g2 even
            *(bf8*)&A1[base + 16 * 8]   = hi;   // g2 odd (+1 row of 16m*8j)
        }
        __syncthreads();   // (1) A1 ready; also guards A2(s-1) reads vs writes below

        // ===== Phase B: GEMM1 (h1 = rbf @ W1), ssp, transpose-store to A2 =====
        {
            const bf8 a0 = *(const bf8*)&A1[(((w * 2 + 0) * 4 + g) * 16 + c0) * 8];
            const bf8 a1 = *(const bf8*)&A1[(((w * 2 + 1) * 4 + g) * 16 + c0) * 8];
            f32x4 hh[8];
            #pragma unroll
            for (int nt = 0; nt < 8; ++nt) {
                const bf8 w0 = *(const bf8*)&W1f[((0 * 4 + g) * D_ + nt * 16 + c0) * 8];
                const bf8 w1 = *(const bf8*)&W1f[((1 * 4 + g) * D_ + nt * 16 + c0) * 8];
                f32x4 acc = {0.f, 0.f, 0.f, 0.f};
                acc = __builtin_amdgcn_mfma_f32_16x16x32_bf16(a0, w0, acc, 0, 0, 0);
                acc = __builtin_amdgcn_mfma_f32_16x16x32_bf16(a1, w1, acc, 0, 0, 0);
                hh[nt] = acc;
            }
            // value (row m' = g*4+r, col k2 = nt*16+c0) -> A2[w][nt>>1][(nt&1)*2+(c0>>3)][m'][c0&7]
            #pragma unroll
            for (int nt = 0; nt < 8; ++nt) {
                const int shb = (((w * 4 + (nt >> 1)) * 4 + ((nt & 1) * 2 + (c0 >> 3))) * 16) * 8 + (c0 & 7);
                #pragma unroll
                for (int r = 0; r < 4; ++r) {
                    const float hv = ssp(hh[nt][r] + b1r[nt]);
                    A2[shb + (g * 4 + r) * 8] = f2bf(hv);
                }
            }
        }
        __syncthreads();   // (2) A2 ready

        // ===== Phase C: GEMM2 (filters = h1 @ W2), ssp, gather*filter, scatter =====
        {
            const bf8 p0 = *(const bf8*)&A2[(((w * 4 + 0) * 4 + g) * 16 + c0) * 8];
            const bf8 p1 = *(const bf8*)&A2[(((w * 4 + 1) * 4 + g) * 16 + c0) * 8];
            const bf8 p2 = *(const bf8*)&A2[(((w * 4 + 2) * 4 + g) * 16 + c0) * 8];
            const bf8 p3 = *(const bf8*)&A2[(((w * 4 + 3) * 4 + g) * 16 + c0) * 8];
            f32x4 facc[8];
            #pragma unroll
            for (int nt = 0; nt < 8; ++nt) {
                const bf8 w0 = *(const bf8*)&W2f[((0 * 4 + g) * D_ + nt * 16 + c0) * 8];
                const bf8 w1 = *(const bf8*)&W2f[((1 * 4 + g) * D_ + nt * 16 + c0) * 8];
                const bf8 w2 = *(const bf8*)&W2f[((2 * 4 + g) * D_ + nt * 16 + c0) * 8];
                const bf8 w3 = *(const bf8*)&W2f[((3 * 4 + g) * D_ + nt * 16 + c0) * 8];
                f32x4 acc = {0.f, 0.f, 0.f, 0.f};
                acc = __builtin_amdgcn_mfma_f32_16x16x32_bf16(p0, w0, acc, 0, 0, 0);
                acc = __builtin_amdgcn_mfma_f32_16x16x32_bf16(p1, w1, acc, 0, 0, 0);
                acc = __builtin_amdgcn_mfma_f32_16x16x32_bf16(p2, w2, acc, 0, 0, 0);
                acc = __builtin_amdgcn_mfma_f32_16x16x32_bf16(p3, w3, acc, 0, 0, 0);
                facc[nt] = acc;
            }
            // epilogue: lane-quad g owns edges ebase + s*4 + r, lane handles cols c0+16*nt
            #pragma unroll
            for (int r = 0; r < 4; ++r) {
                const int e  = ebase + s * 4 + r;
                const int j  = idx_j[e];
                const int sg = seg_i[e];
                const float* row = af_b + (size_t)j * D_ + c0;
                vf8 msg;
                #pragma unroll
                for (int nt = 0; nt < 8; ++nt) {
                    const float fv = ssp(facc[nt][r] + b2r[nt]);
                    msg[nt] = row[nt * 16] * fv;
                }
                if (sg != cur_seg) {
                    if (cur_seg >= 0) {
                        float* o = out_b + (size_t)cur_seg * D_ + c0;
                        #pragma unroll
                        for (int nt = 0; nt < 8; ++nt) atomicAdd(o + nt * 16, pend[nt]);
                    }
                    cur_seg = sg;
                    pend = msg;
                } else {
                    pend += msg;
                }
            }
        }
        // next Phase A writes A1 only after barrier (1); A2 race guarded by (1) too
    }
    if (cur_seg >= 0) {
        float* o = out_b + (size_t)cur_seg * D_ + c0;
        #pragma unroll
        for (int nt = 0; nt < 8; ++nt) atomicAdd(o + nt * 16, pend[nt]);
    }
}

extern "C" void kernel_launch(void* const* d_in, const int* in_sizes, int n_in,
                              void* d_out, int out_size, void* d_ws, size_t ws_size,
                              hipStream_t stream) {
    const float* af      = (const float*)d_in[0];
    const float* dist    = (const float*)d_in[1];
    const int*   idx_j   = (const int*)d_in[2];
    const int*   seg_i   = (const int*)d_in[3];
    const float* centers = (const float*)d_in[4];
    const float* gam     = (const float*)d_in[5];
    const float* W1      = (const float*)d_in[6];
    const float* b1      = (const float*)d_in[7];
    const float* W2      = (const float*)d_in[8];
    const float* b2      = (const float*)d_in[9];
    float* out = (float*)d_out;

    hipMemsetAsync(out, 0, (size_t)out_size * sizeof(float), stream);

    dim3 grid(NBLK, B_);
    cfconv_kernel<<<grid, TPB, 0, stream>>>(af, dist, idx_j, seg_i,
                                            centers, gam, W1, b1, W2, b2, out);
}